// Round 1
// baseline (5411.554 us; speedup 1.0000x reference)
//
#include <hip/hip_runtime.h>
#include <cstddef>
#include <cstdint>

// K-means (Lloyd, 10 fixed iters) for N=1024 points, K=64 centroids, D=98304.
// d_in[0] = x   float32 [1024*98304]
// d_in[1] = centroid float32 [64*98304]
// d_out   = concat(final state [64*98304] f32, last choice [1024] written as f32)
// ws: partial-dot 8MB + dot 256KB + small buffers (~8.7MB total)

#define N_PTS  1024
#define K_C    64
#define D_DIM  98304
#define ITERS  10
#define SPLITD 32          // D split for dot kernel parallelism
#define TN     64          // points per block tile
#define TK     64          // centroids per block tile (all)
#define DC     64          // D-chunk staged in LDS

// ---------------- row squared-norms: one block per row ----------------
__global__ __launch_bounds__(256) void row_norm2_kernel(const float* __restrict__ A,
                                                        float* __restrict__ out) {
    const float* a = A + (size_t)blockIdx.x * D_DIM;
    float s = 0.f;
    for (int d = threadIdx.x * 4; d < D_DIM; d += 256 * 4) {
        float4 v = *reinterpret_cast<const float4*>(a + d);
        s += v.x * v.x + v.y * v.y + v.z * v.z + v.w * v.w;
    }
    #pragma unroll
    for (int off = 32; off; off >>= 1) s += __shfl_down(s, off);
    __shared__ float red[4];
    int lane = threadIdx.x & 63, wid = threadIdx.x >> 6;
    if (lane == 0) red[wid] = s;
    __syncthreads();
    if (threadIdx.x == 0) out[blockIdx.x] = red[0] + red[1] + red[2] + red[3];
}

// ---------------- dot[n][k] partial over a D-segment ----------------
// grid (N/TN, SPLITD), 256 threads. LDS-tiled fp32, 4x4 register tile/thread.
__global__ __launch_bounds__(256) void dot_partial_kernel(const float* __restrict__ X,
                                                          const float* __restrict__ C,
                                                          float* __restrict__ partial) {
    __shared__ float Xs[DC][TN];
    __shared__ float Cs[DC][TK];
    const int nblk = blockIdx.x;
    const int s    = blockIdx.y;
    const int t    = threadIdx.x;
    const int kg = t & 15, ng = t >> 4;
    const int k0 = kg * 4, n0 = ng * 4;
    // staging mapping: col = t&63 (row of X/C tile), db = (t>>6)*16 (16 d's via 4 float4)
    const int col = t & 63;
    const int db  = (t >> 6) * 16;

    float acc[4][4] = {};
    const int d_begin = s * (D_DIM / SPLITD);
    const int d_end   = d_begin + (D_DIM / SPLITD);

    for (int d0 = d_begin; d0 < d_end; d0 += DC) {
        __syncthreads();   // protect LDS from previous iteration's readers
        {
            const float* xrow = X + (size_t)(nblk * TN + col) * D_DIM + d0 + db;
            const float* crow = C + (size_t)col * D_DIM + d0 + db;
            #pragma unroll
            for (int i = 0; i < 4; ++i) {
                float4 v = *reinterpret_cast<const float4*>(xrow + i * 4);
                Xs[db + i * 4 + 0][col] = v.x;
                Xs[db + i * 4 + 1][col] = v.y;
                Xs[db + i * 4 + 2][col] = v.z;
                Xs[db + i * 4 + 3][col] = v.w;
            }
            #pragma unroll
            for (int i = 0; i < 4; ++i) {
                float4 v = *reinterpret_cast<const float4*>(crow + i * 4);
                Cs[db + i * 4 + 0][col] = v.x;
                Cs[db + i * 4 + 1][col] = v.y;
                Cs[db + i * 4 + 2][col] = v.z;
                Cs[db + i * 4 + 3][col] = v.w;
            }
        }
        __syncthreads();
        #pragma unroll 8
        for (int d = 0; d < DC; ++d) {
            float4 xv = *reinterpret_cast<const float4*>(&Xs[d][n0]);
            float4 cv = *reinterpret_cast<const float4*>(&Cs[d][k0]);
            acc[0][0] += xv.x * cv.x; acc[0][1] += xv.x * cv.y;
            acc[0][2] += xv.x * cv.z; acc[0][3] += xv.x * cv.w;
            acc[1][0] += xv.y * cv.x; acc[1][1] += xv.y * cv.y;
            acc[1][2] += xv.y * cv.z; acc[1][3] += xv.y * cv.w;
            acc[2][0] += xv.z * cv.x; acc[2][1] += xv.z * cv.y;
            acc[2][2] += xv.z * cv.z; acc[2][3] += xv.z * cv.w;
            acc[3][0] += xv.w * cv.x; acc[3][1] += xv.w * cv.y;
            acc[3][2] += xv.w * cv.z; acc[3][3] += xv.w * cv.w;
        }
    }
    #pragma unroll
    for (int i = 0; i < 4; ++i)
        #pragma unroll
        for (int j = 0; j < 4; ++j) {
            int n = nblk * TN + n0 + i;
            partial[((size_t)s * N_PTS + n) * K_C + k0 + j] = acc[i][j];
        }
}

// ---------------- reduce split-D partials ----------------
__global__ __launch_bounds__(256) void reduce_dot_kernel(const float* __restrict__ partial,
                                                         float* __restrict__ dot) {
    int i = blockIdx.x * 256 + threadIdx.x;   // 0 .. N*K-1
    float s = 0.f;
    #pragma unroll
    for (int p = 0; p < SPLITD; ++p) s += partial[(size_t)p * N_PTS * K_C + i];
    dot[i] = s;
}

// ---------------- init: per-centroid argmin over points ----------------
// score(n,k) = x2[n] - 2*dot[n][k]  (c2[k] constant over n, drops out)
__global__ __launch_bounds__(256) void argmin_n_kernel(const float* __restrict__ dot,
                                                       const float* __restrict__ x2,
                                                       int* __restrict__ choice_pts) {
    int k = blockIdx.x;
    float best = 3.4e38f; int bi = N_PTS;
    for (int n = threadIdx.x; n < N_PTS; n += 256) {
        float v = fmaf(-2.f, dot[n * K_C + k], x2[n]);
        if (v < best || (v == best && n < bi)) { best = v; bi = n; }
    }
    #pragma unroll
    for (int off = 32; off; off >>= 1) {
        float v2 = __shfl_down(best, off);
        int   i2 = __shfl_down(bi, off);
        if (v2 < best || (v2 == best && i2 < bi)) { best = v2; bi = i2; }
    }
    __shared__ float bv[4]; __shared__ int bix[4];
    int lane = threadIdx.x & 63, wid = threadIdx.x >> 6;
    if (lane == 0) { bv[wid] = best; bix[wid] = bi; }
    __syncthreads();
    if (threadIdx.x == 0) {
        for (int w = 1; w < 4; ++w)
            if (bv[w] < best || (bv[w] == best && bix[w] < bi)) { best = bv[w]; bi = bix[w]; }
        choice_pts[k] = bi;
    }
}

// ---------------- gather snapped centroids: state[k] = X[choice_pts[k]] ----------------
__global__ __launch_bounds__(256) void gather_kernel(const float* __restrict__ X,
                                                     const int* __restrict__ choice_pts,
                                                     float* __restrict__ state) {
    int k = blockIdx.x;
    int c = choice_pts[k];
    size_t d = (size_t)blockIdx.y * 1024 + threadIdx.x * 4;
    float4 v = *reinterpret_cast<const float4*>(X + (size_t)c * D_DIM + d);
    *reinterpret_cast<float4*>(state + (size_t)k * D_DIM + d) = v;
}

// ---------------- per-point argmin over K=64 centroids (one wave / point) ----------------
// score(n,k) = c2[k] - 2*dot[n][k]  (x2[n] drops out). Tie-break: lowest k (JAX argmin).
__global__ __launch_bounds__(256) void assign_kernel(const float* __restrict__ dot,
                                                     const float* __restrict__ c2,
                                                     int* __restrict__ choice) {
    int wid = threadIdx.x >> 6, lane = threadIdx.x & 63;
    int n = blockIdx.x * 4 + wid;
    float v = fmaf(-2.f, dot[n * K_C + lane], c2[lane]);
    int bi = lane;
    #pragma unroll
    for (int m = 32; m; m >>= 1) {
        float v2 = __shfl_xor(v, m);
        int   i2 = __shfl_xor(bi, m);
        if (v2 < v || (v2 == v && i2 < bi)) { v = v2; bi = i2; }
    }
    if (lane == 0) choice[n] = bi;
}

// ---------------- deterministic counting sort of points by cluster ----------------
// Single block; stable rank via O(N^2/threads) LDS scan (few microseconds).
__global__ __launch_bounds__(256) void sort_kernel(const int* __restrict__ choice,
                                                   int* __restrict__ order,
                                                   int* __restrict__ cstart) {
    __shared__ int ch[N_PTS];
    __shared__ int cnt[K_C];
    __shared__ int cst[K_C + 1];
    int t = threadIdx.x;
    if (t < K_C) cnt[t] = 0;
    __syncthreads();
    for (int n = t; n < N_PTS; n += 256) {
        int c = choice[n];
        ch[n] = c;
        atomicAdd(&cnt[c], 1);    // integer atomic: deterministic result
    }
    __syncthreads();
    if (t == 0) {
        int a = 0;
        for (int k = 0; k < K_C; ++k) { cst[k] = a; a += cnt[k]; }
        cst[K_C] = a;
    }
    __syncthreads();
    if (t <= K_C) cstart[t] = cst[t];
    for (int n = t; n < N_PTS; n += 256) {
        int c = ch[n], r = 0;
        for (int m = 0; m < n; ++m) r += (ch[m] == c);
        order[cst[c] + r] = n;
    }
}

// ---------------- fused segment-sum + mean update (in place on state) ----------------
// Empty clusters keep old centroid (match jnp.where(counts>0, sums/counts, state)).
__global__ __launch_bounds__(256) void segsum_update_kernel(const float* __restrict__ X,
                                                            const int* __restrict__ order,
                                                            const int* __restrict__ cstart,
                                                            float* __restrict__ state) {
    int k = blockIdx.x;
    int b = cstart[k], e = cstart[k + 1];
    if (b == e) return;                      // empty cluster: keep old state
    size_t d = (size_t)blockIdx.y * 1024 + threadIdx.x * 4;
    float4 acc = {0.f, 0.f, 0.f, 0.f};
    for (int i = b; i < e; ++i) {
        const float4 v = *reinterpret_cast<const float4*>(X + (size_t)order[i] * D_DIM + d);
        acc.x += v.x; acc.y += v.y; acc.z += v.z; acc.w += v.w;
    }
    float c = (float)(e - b);
    acc.x /= c; acc.y /= c; acc.z /= c; acc.w /= c;
    *reinterpret_cast<float4*>(state + (size_t)k * D_DIM + d) = acc;
}

// ---------------- write last-iteration assignments as float ----------------
__global__ __launch_bounds__(256) void choice_out_kernel(const int* __restrict__ choice,
                                                         float* __restrict__ out) {
    int n = blockIdx.x * 256 + threadIdx.x;
    if (n < N_PTS) out[n] = (float)choice[n];
}

extern "C" void kernel_launch(void* const* d_in, const int* in_sizes, int n_in,
                              void* d_out, int out_size, void* d_ws, size_t ws_size,
                              hipStream_t stream) {
    const float* X  = (const float*)d_in[0];
    const float* C0 = (const float*)d_in[1];
    float* state      = (float*)d_out;                       // [K][D], final centroids
    float* out_choice = state + (size_t)K_C * D_DIM;         // [N] as floats

    // workspace layout (~8.7 MB)
    char* w = (char*)d_ws;
    float* partial = (float*)w;                              // SPLITD*N*K floats = 8 MB
    size_t off = (size_t)SPLITD * N_PTS * K_C * 4;
    float* dotb = (float*)(w + off); off += (size_t)N_PTS * K_C * 4;   // 256 KB
    float* x2   = (float*)(w + off); off += (size_t)N_PTS * 4;
    float* c2   = (float*)(w + off); off += (size_t)K_C * 4;
    int* choice = (int*)(w + off);   off += (size_t)N_PTS * 4;
    int* order  = (int*)(w + off);   off += (size_t)N_PTS * 4;
    int* cstart = (int*)(w + off);   off += (size_t)(K_C + 1) * 4;

    dim3 b256(256);

    // x squared norms (constant across iterations)
    row_norm2_kernel<<<N_PTS, b256, 0, stream>>>(X, x2);

    // ---- init ('resuming' branch): snap each centroid to its nearest sample ----
    dot_partial_kernel<<<dim3(N_PTS / TN, SPLITD), b256, 0, stream>>>(X, C0, partial);
    reduce_dot_kernel<<<dim3(N_PTS * K_C / 256), b256, 0, stream>>>(partial, dotb);
    argmin_n_kernel<<<K_C, b256, 0, stream>>>(dotb, x2, choice);   // choice reused as choice_pts
    gather_kernel<<<dim3(K_C, D_DIM / 1024), b256, 0, stream>>>(X, choice, state);

    // ---- 10 Lloyd iterations ----
    for (int it = 0; it < ITERS; ++it) {
        row_norm2_kernel<<<K_C, b256, 0, stream>>>(state, c2);
        dot_partial_kernel<<<dim3(N_PTS / TN, SPLITD), b256, 0, stream>>>(X, state, partial);
        reduce_dot_kernel<<<dim3(N_PTS * K_C / 256), b256, 0, stream>>>(partial, dotb);
        assign_kernel<<<dim3(N_PTS / 4), b256, 0, stream>>>(dotb, c2, choice);
        sort_kernel<<<1, b256, 0, stream>>>(choice, order, cstart);
        segsum_update_kernel<<<dim3(K_C, D_DIM / 1024), b256, 0, stream>>>(X, order, cstart, state);
    }

    choice_out_kernel<<<dim3(N_PTS / 256 + (N_PTS % 256 != 0)), b256, 0, stream>>>(choice, out_choice);
}

// Round 2
// 2482.901 us; speedup vs baseline: 2.1795x; 2.1795x over previous
//
#include <hip/hip_runtime.h>
#include <cstddef>
#include <cstdint>

// K-means (Lloyd, 10 fixed iters): N=1024 pts, K=64 centroids, D=98304.
// d_in[0]=x f32[1024*98304], d_in[1]=centroid f32[64*98304]
// d_out = concat(final state [64*98304] f32, last choice [1024] as f32)
//
// Round 2: (a) dot GEMM via bf16 hi/lo x3 MFMA (fp32-accurate to ~2^-17) with
// register-prefetch pipeline; (b) incremental segment-sum update driven by a
// deterministic change list (replaces full segsum + O(N^2) sort).

#define N_PTS  1024
#define K_C    64
#define D_DIM  98304
#define ITERS  10
#define SPLITD 32          // D-split for dot kernel (partial buffer = 8 MB)
#define BM     64          // points per block tile
#define TK     64          // centroids (all) per block tile
#define DC     64          // D-chunk staged in LDS per step
#define LDSP   72          // padded LDS row stride (bf16 elems): 144 B -> ~conflict-free frag reads

typedef __attribute__((ext_vector_type(8))) short bf16x8;   // 8 bf16 in 4 VGPRs
typedef __attribute__((ext_vector_type(4))) float f32x4;

__device__ __forceinline__ unsigned short f2bf(float x) {   // RNE truncate f32->bf16
    unsigned u = __float_as_uint(x);
    u = (u + 0x7FFFu + ((u >> 16) & 1u)) >> 16;
    return (unsigned short)u;
}
__device__ __forceinline__ float bf2f(unsigned short b) {
    return __uint_as_float((unsigned)b << 16);
}
__device__ __forceinline__ void cvt2(float x, unsigned short& h, unsigned short& l) {
    h = f2bf(x);
    l = f2bf(x - bf2f(h));
}

// ---------------- row squared-norms: one block per row ----------------
__global__ __launch_bounds__(256) void row_norm2_kernel(const float* __restrict__ A,
                                                        float* __restrict__ out) {
    const float* a = A + (size_t)blockIdx.x * D_DIM;
    float s = 0.f;
    for (int d = threadIdx.x * 4; d < D_DIM; d += 256 * 4) {
        float4 v = *reinterpret_cast<const float4*>(a + d);
        s += v.x * v.x + v.y * v.y + v.z * v.z + v.w * v.w;
    }
    #pragma unroll
    for (int off = 32; off; off >>= 1) s += __shfl_down(s, off);
    __shared__ float red[4];
    int lane = threadIdx.x & 63, wid = threadIdx.x >> 6;
    if (lane == 0) red[wid] = s;
    __syncthreads();
    if (threadIdx.x == 0) out[blockIdx.x] = red[0] + red[1] + red[2] + red[3];
}

// ---------------- dot[n][k] partial via bf16 hi/lo x3 MFMA ----------------
// grid (N/BM, SPLITD), 256 thr = 4 waves. Wave w owns 16-row strip x 64 cols.
// Staging converts fp32 -> (hi,lo) bf16 tiles in LDS; next chunk's global
// loads are issued before the MFMAs (register prefetch).
__global__ __launch_bounds__(256) void mfma_dot_kernel(const float* __restrict__ X,
                                                       const float* __restrict__ S,
                                                       float* __restrict__ partial) {
    __shared__ alignas(16) short Ah[BM][LDSP];
    __shared__ alignas(16) short Al[BM][LDSP];
    __shared__ alignas(16) short Bh[TK][LDSP];
    __shared__ alignas(16) short Bl[TK][LDSP];

    const int nblk = blockIdx.x, seg = blockIdx.y;
    const int t = threadIdx.x;
    const int wid = t >> 6, lane = t & 63;
    const int srow = t >> 4;           // 0..15  (staging row within 16-row pass)
    const int scol = (t & 15) * 4;     // 0..60  (float4 column)

    const int d_begin = seg * (D_DIM / SPLITD);
    const int NCH = (D_DIM / SPLITD) / DC;          // 48 chunks

    const float* xbase = X + (size_t)(nblk * BM) * D_DIM;
    float4 xr[4], sr[4];

    auto load_chunk = [&](int d0) {
        #pragma unroll
        for (int p = 0; p < 4; ++p) {
            int row = p * 16 + srow;
            xr[p] = *reinterpret_cast<const float4*>(xbase + (size_t)row * D_DIM + d0 + scol);
            sr[p] = *reinterpret_cast<const float4*>(S + (size_t)row * D_DIM + d0 + scol);
        }
    };
    auto store_chunk = [&]() {
        #pragma unroll
        for (int p = 0; p < 4; ++p) {
            int row = p * 16 + srow;
            ushort4 hx, lx, hs, ls;
            cvt2(xr[p].x, hx.x, lx.x); cvt2(xr[p].y, hx.y, lx.y);
            cvt2(xr[p].z, hx.z, lx.z); cvt2(xr[p].w, hx.w, lx.w);
            cvt2(sr[p].x, hs.x, ls.x); cvt2(sr[p].y, hs.y, ls.y);
            cvt2(sr[p].z, hs.z, ls.z); cvt2(sr[p].w, hs.w, ls.w);
            *reinterpret_cast<ushort4*>(&Ah[row][scol]) = hx;
            *reinterpret_cast<ushort4*>(&Al[row][scol]) = lx;
            *reinterpret_cast<ushort4*>(&Bh[row][scol]) = hs;
            *reinterpret_cast<ushort4*>(&Bl[row][scol]) = ls;
        }
    };

    f32x4 acc[4];
    #pragma unroll
    for (int i = 0; i < 4; ++i) acc[i] = f32x4{0.f, 0.f, 0.f, 0.f};

    load_chunk(d_begin);
    for (int c = 0; c < NCH; ++c) {
        __syncthreads();              // prior chunk's frag reads complete
        store_chunk();
        __syncthreads();              // tiles visible
        if (c + 1 < NCH) load_chunk(d_begin + (c + 1) * DC);   // prefetch (overlaps MFMA)

        const int ar = wid * 16 + (lane & 15);
        #pragma unroll
        for (int ks = 0; ks < 2; ++ks) {
            const int ko = ks * 32 + (lane >> 4) * 8;
            bf16x8 ah = *reinterpret_cast<const bf16x8*>(&Ah[ar][ko]);
            bf16x8 al = *reinterpret_cast<const bf16x8*>(&Al[ar][ko]);
            #pragma unroll
            for (int nb = 0; nb < 4; ++nb) {
                const int br = nb * 16 + (lane & 15);
                bf16x8 bh = *reinterpret_cast<const bf16x8*>(&Bh[br][ko]);
                bf16x8 bl = *reinterpret_cast<const bf16x8*>(&Bl[br][ko]);
                acc[nb] = __builtin_amdgcn_mfma_f32_16x16x32_bf16(ah, bh, acc[nb], 0, 0, 0);
                acc[nb] = __builtin_amdgcn_mfma_f32_16x16x32_bf16(ah, bl, acc[nb], 0, 0, 0);
                acc[nb] = __builtin_amdgcn_mfma_f32_16x16x32_bf16(al, bh, acc[nb], 0, 0, 0);
            }
        }
    }

    // C/D layout (m89-verified): col = lane&15, row = (lane>>4)*4 + reg
    #pragma unroll
    for (int nb = 0; nb < 4; ++nb)
        #pragma unroll
        for (int r = 0; r < 4; ++r) {
            int row = wid * 16 + (lane >> 4) * 4 + r;
            int col = nb * 16 + (lane & 15);
            int n = nblk * BM + row;
            partial[((size_t)seg * N_PTS + n) * K_C + col] = acc[nb][r];
        }
}

// ---------------- reduce split-D partials ----------------
__global__ __launch_bounds__(256) void reduce_dot_kernel(const float* __restrict__ partial,
                                                         float* __restrict__ dot) {
    int i = blockIdx.x * 256 + threadIdx.x;
    float s = 0.f;
    #pragma unroll
    for (int p = 0; p < SPLITD; ++p) s += partial[(size_t)p * N_PTS * K_C + i];
    dot[i] = s;
}

// ---------------- init: per-centroid argmin over points ----------------
__global__ __launch_bounds__(256) void argmin_n_kernel(const float* __restrict__ dot,
                                                       const float* __restrict__ x2,
                                                       int* __restrict__ choice_pts) {
    int k = blockIdx.x;
    float best = 3.4e38f; int bi = N_PTS;
    for (int n = threadIdx.x; n < N_PTS; n += 256) {
        float v = fmaf(-2.f, dot[n * K_C + k], x2[n]);
        if (v < best || (v == best && n < bi)) { best = v; bi = n; }
    }
    #pragma unroll
    for (int off = 32; off; off >>= 1) {
        float v2 = __shfl_down(best, off);
        int   i2 = __shfl_down(bi, off);
        if (v2 < best || (v2 == best && i2 < bi)) { best = v2; bi = i2; }
    }
    __shared__ float bv[4]; __shared__ int bix[4];
    int lane = threadIdx.x & 63, wid = threadIdx.x >> 6;
    if (lane == 0) { bv[wid] = best; bix[wid] = bi; }
    __syncthreads();
    if (threadIdx.x == 0) {
        for (int w = 1; w < 4; ++w)
            if (bv[w] < best || (bv[w] == best && bix[w] < bi)) { best = bv[w]; bi = bix[w]; }
        choice_pts[k] = bi;
    }
}

// ---------------- gather snapped centroids ----------------
__global__ __launch_bounds__(256) void gather_kernel(const float* __restrict__ X,
                                                     const int* __restrict__ choice_pts,
                                                     float* __restrict__ state) {
    int k = blockIdx.x;
    int c = choice_pts[k];
    size_t d = (size_t)blockIdx.y * 1024 + threadIdx.x * 4;
    float4 v = *reinterpret_cast<const float4*>(X + (size_t)c * D_DIM + d);
    *reinterpret_cast<float4*>(state + (size_t)k * D_DIM + d) = v;
}

// ---------------- per-point argmin over K=64 (one wave / point) ----------------
__global__ __launch_bounds__(256) void assign_kernel(const float* __restrict__ dot,
                                                     const float* __restrict__ c2,
                                                     int* __restrict__ choice) {
    int wid = threadIdx.x >> 6, lane = threadIdx.x & 63;
    int n = blockIdx.x * 4 + wid;
    float v = fmaf(-2.f, dot[n * K_C + lane], c2[lane]);
    int bi = lane;
    #pragma unroll
    for (int m = 32; m; m >>= 1) {
        float v2 = __shfl_xor(v, m);
        int   i2 = __shfl_xor(bi, m);
        if (v2 < v || (v2 == v && i2 < bi)) { v = v2; bi = i2; }
    }
    if (lane == 0) choice[n] = bi;
}

// ---------------- init prev-assignment state ----------------
__global__ __launch_bounds__(256) void init_prev_kernel(int* __restrict__ chp,
                                                        int* __restrict__ ctp) {
    int t = blockIdx.x * 256 + threadIdx.x;
    if (t < N_PTS) chp[t] = -1;
    if (t < K_C)   ctp[t] = 0;
}

// ---------------- change list + new counts (single block, deterministic) ----------------
__global__ __launch_bounds__(256) void changes_kernel(const int* __restrict__ ch_new,
                                                      const int* __restrict__ ch_prev,
                                                      int* __restrict__ chg_n,
                                                      int* __restrict__ chg_old,
                                                      int* __restrict__ chg_new,
                                                      int* __restrict__ nchg,
                                                      int* __restrict__ counts_new) {
    __shared__ int cnt[K_C];
    __shared__ int pre[256];
    int t = threadIdx.x;
    if (t < K_C) cnt[t] = 0;
    __syncthreads();
    int f[4], po[4], pn[4];
    int loc = 0;
    #pragma unroll
    for (int i = 0; i < 4; ++i) {
        int n = t * 4 + i;
        int nn = ch_new[n], pp = ch_prev[n];
        atomicAdd(&cnt[nn], 1);                 // integer: deterministic
        pn[i] = nn; po[i] = pp;
        f[i] = (nn != pp) ? 1 : 0;
        loc += f[i];
    }
    pre[t] = loc;
    __syncthreads();
    for (int off = 1; off < 256; off <<= 1) {   // Hillis-Steele inclusive scan
        int v = (t >= off) ? pre[t - off] : 0;
        __syncthreads();
        pre[t] += v;
        __syncthreads();
    }
    int w = pre[t] - loc;                       // exclusive base, n-ordered
    #pragma unroll
    for (int i = 0; i < 4; ++i) {
        if (f[i]) { chg_n[w] = t * 4 + i; chg_old[w] = po[i]; chg_new[w] = pn[i]; ++w; }
    }
    if (t == 255) *nchg = pre[255];
    __syncthreads();
    if (t < K_C) counts_new[t] = cnt[t];
}

// ---------------- incremental state update ----------------
// sums[k] reconstructed as state[k]*count_prev[k]; apply +/- for changed pts
// in list order (deterministic); write mean only if touched and nonempty.
__global__ __launch_bounds__(256) void update_state_kernel(const float* __restrict__ X,
                                                           const int* __restrict__ chg_n,
                                                           const int* __restrict__ chg_old,
                                                           const int* __restrict__ chg_new,
                                                           const int* __restrict__ nchg_p,
                                                           const int* __restrict__ counts_new,
                                                           const int* __restrict__ counts_prev,
                                                           float* __restrict__ state) {
    const int k = blockIdx.x;
    const int m = *nchg_p;
    const int cn = counts_new[k], cp = counts_prev[k];
    const size_t d = (size_t)blockIdx.y * 1024 + threadIdx.x * 4;
    float* sp = state + (size_t)k * D_DIM + d;

    float sx = 0.f, sy = 0.f, sz = 0.f, sw = 0.f;
    if (cp > 0) {
        float4 st = *reinterpret_cast<const float4*>(sp);
        float c = (float)cp;
        sx = st.x * c; sy = st.y * c; sz = st.z * c; sw = st.w * c;
    }
    bool touched = false;
    for (int i = 0; i < m; ++i) {
        int ko = chg_old[i], kn = chg_new[i];
        if (ko != k && kn != k) continue;
        touched = true;
        const float4 v = *reinterpret_cast<const float4*>(X + (size_t)chg_n[i] * D_DIM + d);
        float sgn = (kn == k) ? 1.f : -1.f;
        sx += sgn * v.x; sy += sgn * v.y; sz += sgn * v.z; sw += sgn * v.w;
    }
    if (touched && cn > 0) {
        float c = (float)cn;
        float4 o;
        o.x = sx / c; o.y = sy / c; o.z = sz / c; o.w = sw / c;
        *reinterpret_cast<float4*>(sp) = o;
    }
}

// ---------------- write last-iteration assignments as float ----------------
__global__ __launch_bounds__(256) void choice_out_kernel(const int* __restrict__ choice,
                                                         float* __restrict__ out) {
    int n = blockIdx.x * 256 + threadIdx.x;
    if (n < N_PTS) out[n] = (float)choice[n];
}

extern "C" void kernel_launch(void* const* d_in, const int* in_sizes, int n_in,
                              void* d_out, int out_size, void* d_ws, size_t ws_size,
                              hipStream_t stream) {
    const float* X  = (const float*)d_in[0];
    const float* C0 = (const float*)d_in[1];
    float* state      = (float*)d_out;                       // [K][D]
    float* out_choice = state + (size_t)K_C * D_DIM;         // [N]

    // workspace layout (~8.3 MB, under proven ws floor)
    char* w = (char*)d_ws;
    size_t off = 0;
    float* partial = (float*)(w + off); off += (size_t)SPLITD * N_PTS * K_C * 4;  // 8 MB
    float* dotb    = (float*)(w + off); off += (size_t)N_PTS * K_C * 4;           // 256 KB
    float* x2      = (float*)(w + off); off += (size_t)N_PTS * 4;
    float* c2      = (float*)(w + off); off += 256;
    int* cpts      = (int*)(w + off);   off += 256;
    int* ch[2];
    ch[0] = (int*)(w + off); off += (size_t)N_PTS * 4;
    ch[1] = (int*)(w + off); off += (size_t)N_PTS * 4;
    int* ct[2];
    ct[0] = (int*)(w + off); off += 256;
    ct[1] = (int*)(w + off); off += 256;
    int* chg_n   = (int*)(w + off); off += (size_t)N_PTS * 4;
    int* chg_old = (int*)(w + off); off += (size_t)N_PTS * 4;
    int* chg_new = (int*)(w + off); off += (size_t)N_PTS * 4;
    int* nchg    = (int*)(w + off); off += 256;

    dim3 b256(256);

    row_norm2_kernel<<<N_PTS, b256, 0, stream>>>(X, x2);

    // ---- init ('resuming'): snap each centroid to its nearest sample ----
    mfma_dot_kernel<<<dim3(N_PTS / BM, SPLITD), b256, 0, stream>>>(X, C0, partial);
    reduce_dot_kernel<<<dim3(N_PTS * K_C / 256), b256, 0, stream>>>(partial, dotb);
    argmin_n_kernel<<<K_C, b256, 0, stream>>>(dotb, x2, cpts);
    gather_kernel<<<dim3(K_C, D_DIM / 1024), b256, 0, stream>>>(X, cpts, state);
    init_prev_kernel<<<dim3(4), b256, 0, stream>>>(ch[0], ct[0]);

    // ---- 10 Lloyd iterations (ping-pong choice/counts buffers) ----
    for (int it = 0; it < ITERS; ++it) {
        int prev = it & 1, cur = 1 - prev;
        row_norm2_kernel<<<K_C, b256, 0, stream>>>(state, c2);
        mfma_dot_kernel<<<dim3(N_PTS / BM, SPLITD), b256, 0, stream>>>(X, state, partial);
        reduce_dot_kernel<<<dim3(N_PTS * K_C / 256), b256, 0, stream>>>(partial, dotb);
        assign_kernel<<<dim3(N_PTS / 4), b256, 0, stream>>>(dotb, c2, ch[cur]);
        changes_kernel<<<1, b256, 0, stream>>>(ch[cur], ch[prev], chg_n, chg_old, chg_new,
                                               nchg, ct[cur]);
        update_state_kernel<<<dim3(K_C, D_DIM / 1024), b256, 0, stream>>>(
            X, chg_n, chg_old, chg_new, nchg, ct[cur], ct[prev], state);
    }

    choice_out_kernel<<<dim3(N_PTS / 256), b256, 0, stream>>>(ch[0], out_choice);
}